// Round 1
// baseline (444.332 us; speedup 1.0000x reference)
//
#include <hip/hip_runtime.h>
#include <math.h>

#define B_   2
#define NQ_  10000
#define NV_  21760
#define EMB  256
#define NH   8
#define HD   32

// ---------------------------------------------------------------------------
// Generic fp32 GEMM: C[M,N] = A[M,256] @ W[256,N] + bias[N]
// 64x64 tile, 256 threads, 4x4 accumulators per thread. K fixed at 256.
// ---------------------------------------------------------------------------
__global__ __launch_bounds__(256) void gemm_bias(
    const float* __restrict__ A, const float* __restrict__ W,
    const float* __restrict__ bias, float* __restrict__ C,
    int M, int N) {
  constexpr int K = 256, BM = 64, BN = 64, BK = 16;
  __shared__ float As[BM][BK + 1];
  __shared__ float Ws[BK][BN];

  const int tid = threadIdx.x;
  const int tx = tid & 15, ty = tid >> 4;
  const int row0 = blockIdx.x * BM;
  const int col0 = blockIdx.y * BN;

  // A-tile load mapping: each thread loads one float4 (row ar, cols ac..ac+3)
  const int ar = tid >> 2, ac = (tid & 3) << 2;
  // W-tile load mapping: row kr, cols wc..wc+3
  const int kr = tid >> 4, wc = (tid & 15) << 2;

  float acc[4][4] = {};

  for (int kk = 0; kk < K; kk += BK) {
    float4 av = make_float4(0.f, 0.f, 0.f, 0.f);
    if (row0 + ar < M)
      av = *(const float4*)&A[(size_t)(row0 + ar) * K + kk + ac];
    As[ar][ac + 0] = av.x;
    As[ar][ac + 1] = av.y;
    As[ar][ac + 2] = av.z;
    As[ar][ac + 3] = av.w;

    float4 wv = *(const float4*)&W[(size_t)(kk + kr) * N + col0 + wc];
    *(float4*)&Ws[kr][wc] = wv;
    __syncthreads();

#pragma unroll
    for (int k = 0; k < BK; ++k) {
      float a0 = As[ty * 4 + 0][k];
      float a1 = As[ty * 4 + 1][k];
      float a2 = As[ty * 4 + 2][k];
      float a3 = As[ty * 4 + 3][k];
      float4 bv = *(const float4*)&Ws[k][tx * 4];
      acc[0][0] += a0 * bv.x; acc[0][1] += a0 * bv.y; acc[0][2] += a0 * bv.z; acc[0][3] += a0 * bv.w;
      acc[1][0] += a1 * bv.x; acc[1][1] += a1 * bv.y; acc[1][2] += a1 * bv.z; acc[1][3] += a1 * bv.w;
      acc[2][0] += a2 * bv.x; acc[2][1] += a2 * bv.y; acc[2][2] += a2 * bv.z; acc[2][3] += a2 * bv.w;
      acc[3][0] += a3 * bv.x; acc[3][1] += a3 * bv.y; acc[3][2] += a3 * bv.z; acc[3][3] += a3 * bv.w;
    }
    __syncthreads();
  }

  float4 bb = *(const float4*)&bias[col0 + tx * 4];
#pragma unroll
  for (int i = 0; i < 4; ++i) {
    int row = row0 + ty * 4 + i;
    if (row < M) {
      float4 o;
      o.x = acc[i][0] + bb.x;
      o.y = acc[i][1] + bb.y;
      o.z = acc[i][2] + bb.z;
      o.w = acc[i][3] + bb.w;
      *(float4*)&C[(size_t)row * N + col0 + tx * 4] = o;
    }
  }
}

// ---------------------------------------------------------------------------
// Sampling: one block per (b,q). Thread t -> head h = t>>5, channel d = t&31.
// v:    (B, NV, 8, 32)
// off:  (B, NQ, 8, 4, 4, 2)  flat (B*NQ, 256)
// attn: (B, NQ, 8, 4, 4)     flat (B*NQ, 128) logits
// tmp:  (B, NQ, 256)
// ---------------------------------------------------------------------------
__device__ __forceinline__ float fetch_corner(const float* vl, int x, int y,
                                              int Wl, int Hl) {
  if (x < 0 || x >= Wl || y < 0 || y >= Hl) return 0.f;
  return vl[(size_t)(y * Wl + x) * EMB];
}

__global__ __launch_bounds__(256) void msda_sample(
    const float* __restrict__ v, const float* __restrict__ off,
    const float* __restrict__ attnlg, float* __restrict__ tmp) {
  const int t = threadIdx.x;
  const int h = t >> 5, d = t & 31;
  const int bq = blockIdx.x;              // b*NQ + q
  const int b = bq / NQ_;

  const float* offq = off + (size_t)bq * 256 + h * 32;
  const float* attq = attnlg + (size_t)bq * 128 + h * 16;

  constexpr int LS[4] = {0, 16384, 20480, 21504};
  constexpr int LW[4] = {128, 64, 32, 16};

  float acc = 0.f;
#pragma unroll
  for (int l = 0; l < 4; ++l) {
    const int Wl = LW[l], Hl = LW[l];
    const float* vl = v + ((size_t)b * NV_ + LS[l]) * EMB + h * 32 + d;

    // softmax over the 4 points of this (h, l)
    float lg0 = attq[l * 4 + 0];
    float lg1 = attq[l * 4 + 1];
    float lg2 = attq[l * 4 + 2];
    float lg3 = attq[l * 4 + 3];
    float m = fmaxf(fmaxf(lg0, lg1), fmaxf(lg2, lg3));
    float e0 = expf(lg0 - m), e1 = expf(lg1 - m);
    float e2 = expf(lg2 - m), e3 = expf(lg3 - m);
    float inv = 1.f / (e0 + e1 + e2 + e3);
    float wts[4] = {e0 * inv, e1 * inv, e2 * inv, e3 * inv};

#pragma unroll
    for (int p = 0; p < 4; ++p) {
      float gx = offq[(l * 4 + p) * 2 + 0];
      float gy = offq[(l * 4 + p) * 2 + 1];
      float px = (gx + 1.f) * 0.5f * (float)(Wl - 1);
      float py = (gy + 1.f) * 0.5f * (float)(Hl - 1);
      float x0f = floorf(px), y0f = floorf(py);
      float wx = px - x0f, wy = py - y0f;
      int x0 = (int)x0f, y0 = (int)y0f;

      float v00 = fetch_corner(vl, x0,     y0,     Wl, Hl);
      float v01 = fetch_corner(vl, x0 + 1, y0,     Wl, Hl);
      float v10 = fetch_corner(vl, x0,     y0 + 1, Wl, Hl);
      float v11 = fetch_corner(vl, x0 + 1, y0 + 1, Wl, Hl);

      float top = v00 * (1.f - wx) + v01 * wx;
      float bot = v10 * (1.f - wx) + v11 * wx;
      acc += wts[p] * (top * (1.f - wy) + bot * wy);
    }
  }
  tmp[(size_t)bq * 256 + t] = acc;
}

// ---------------------------------------------------------------------------
extern "C" void kernel_launch(void* const* d_in, const int* in_sizes, int n_in,
                              void* d_out, int out_size, void* d_ws, size_t ws_size,
                              hipStream_t stream) {
  const float* query  = (const float*)d_in[0];
  // d_in[1] = key (unused by the reference)
  const float* value  = (const float*)d_in[2];
  const float* W_off  = (const float*)d_in[3];
  const float* b_off  = (const float*)d_in[4];
  const float* W_attn = (const float*)d_in[5];
  const float* b_attn = (const float*)d_in[6];
  const float* W_v    = (const float*)d_in[7];
  const float* b_v    = (const float*)d_in[8];
  const float* W_out  = (const float*)d_in[9];
  const float* b_out  = (const float*)d_in[10];
  float* out = (float*)d_out;

  float* ws = (float*)d_ws;
  float* v_ws   = ws;                               // 43520*256 = 11,141,120
  float* off_ws = v_ws + (size_t)B_ * NV_ * EMB;    // 20000*256 =  5,120,000
  float* att_ws = off_ws + (size_t)B_ * NQ_ * EMB;  // 20000*128 =  2,560,000
  float* tmp_ws = att_ws + (size_t)B_ * NQ_ * 128;  // 20000*256 =  5,120,000

  dim3 blk(256);

  {  // v = value @ W_v + b_v
    int M = B_ * NV_;
    gemm_bias<<<dim3((M + 63) / 64, EMB / 64), blk, 0, stream>>>(
        value, W_v, b_v, v_ws, M, EMB);
  }
  {  // off = query @ W_off + b_off ; attn = query @ W_attn + b_attn
    int M = B_ * NQ_;
    gemm_bias<<<dim3((M + 63) / 64, EMB / 64), blk, 0, stream>>>(
        query, W_off, b_off, off_ws, M, EMB);
    gemm_bias<<<dim3((M + 63) / 64, 128 / 64), blk, 0, stream>>>(
        query, W_attn, b_attn, att_ws, M, 128);
  }
  // bilinear sampling + softmax-weighted accumulation
  msda_sample<<<dim3(B_ * NQ_), blk, 0, stream>>>(v_ws, off_ws, att_ws, tmp_ws);

  {  // out = tmp @ W_out + b_out
    int M = B_ * NQ_;
    gemm_bias<<<dim3((M + 63) / 64, EMB / 64), blk, 0, stream>>>(
        tmp_ws, W_out, b_out, out, M, EMB);
  }
}

// Round 3
// 284.621 us; speedup vs baseline: 1.5611x; 1.5611x over previous
//
#include <hip/hip_runtime.h>
#include <math.h>

#define B_   2
#define NQ_  10000
#define NV_  21760
#define EMB  256
#define NH   8
#define HD   32

// ---------------------------------------------------------------------------
// Generic fp32 GEMM: C[M,N] = A[M,256] @ W[256,N] + bias[N]
// 64x64 tile, 256 threads, 4x4 accumulators per thread. K fixed at 256.
// ---------------------------------------------------------------------------
__global__ __launch_bounds__(256) void gemm_bias(
    const float* __restrict__ A, const float* __restrict__ W,
    const float* __restrict__ bias, float* __restrict__ C,
    int M, int N) {
  constexpr int K = 256, BM = 64, BN = 64, BK = 16;
  __shared__ float As[BM][BK + 1];
  __shared__ float Ws[BK][BN];

  const int tid = threadIdx.x;
  const int tx = tid & 15, ty = tid >> 4;
  const int row0 = blockIdx.x * BM;
  const int col0 = blockIdx.y * BN;

  const int ar = tid >> 2, ac = (tid & 3) << 2;
  const int kr = tid >> 4, wc = (tid & 15) << 2;

  float acc[4][4] = {};

  for (int kk = 0; kk < K; kk += BK) {
    float4 av = make_float4(0.f, 0.f, 0.f, 0.f);
    if (row0 + ar < M)
      av = *(const float4*)&A[(size_t)(row0 + ar) * K + kk + ac];
    As[ar][ac + 0] = av.x;
    As[ar][ac + 1] = av.y;
    As[ar][ac + 2] = av.z;
    As[ar][ac + 3] = av.w;

    float4 wv = *(const float4*)&W[(size_t)(kk + kr) * N + col0 + wc];
    *(float4*)&Ws[kr][wc] = wv;
    __syncthreads();

#pragma unroll
    for (int k = 0; k < BK; ++k) {
      float a0 = As[ty * 4 + 0][k];
      float a1 = As[ty * 4 + 1][k];
      float a2 = As[ty * 4 + 2][k];
      float a3 = As[ty * 4 + 3][k];
      float4 bv = *(const float4*)&Ws[k][tx * 4];
      acc[0][0] += a0 * bv.x; acc[0][1] += a0 * bv.y; acc[0][2] += a0 * bv.z; acc[0][3] += a0 * bv.w;
      acc[1][0] += a1 * bv.x; acc[1][1] += a1 * bv.y; acc[1][2] += a1 * bv.z; acc[1][3] += a1 * bv.w;
      acc[2][0] += a2 * bv.x; acc[2][1] += a2 * bv.y; acc[2][2] += a2 * bv.z; acc[2][3] += a2 * bv.w;
      acc[3][0] += a3 * bv.x; acc[3][1] += a3 * bv.y; acc[3][2] += a3 * bv.z; acc[3][3] += a3 * bv.w;
    }
    __syncthreads();
  }

  float4 bb = *(const float4*)&bias[col0 + tx * 4];
#pragma unroll
  for (int i = 0; i < 4; ++i) {
    int row = row0 + ty * 4 + i;
    if (row < M) {
      float4 o;
      o.x = acc[i][0] + bb.x;
      o.y = acc[i][1] + bb.y;
      o.z = acc[i][2] + bb.z;
      o.w = acc[i][3] + bb.w;
      *(float4*)&C[(size_t)row * N + col0 + tx * 4] = o;
    }
  }
}

// ---------------------------------------------------------------------------
// Sampling v2b: one 64-lane wave per query. lane -> head h = lane>>3,
// 4-channel group c4 = lane&7. All gathers are float4 (16 B); the 8 lanes of
// a head read 128 B contiguous per corner. Block = 256 threads = 4 queries.
// Each corner coordinate is clamped INDEPENDENTLY (R2 bug: x1 derived from
// clamped x0 read the wrong column when x0 == -1).
// v4:   (B, NV, 64) float4   [= (B,NV,8h,32d) floats]
// off:  (B*NQ, 256) floats   [(h,l,p,2)]
// attn: (B*NQ, 128) floats   [(h,l,p) logits]
// tmp4: (B*NQ, 64) float4
// ---------------------------------------------------------------------------
__global__ __launch_bounds__(256) void msda_sample2(
    const float4* __restrict__ v4, const float* __restrict__ off,
    const float* __restrict__ attnlg, float4* __restrict__ tmp4) {
  const int lane = threadIdx.x & 63;
  const int bq = blockIdx.x * 4 + (threadIdx.x >> 6);
  const int b = bq / NQ_;
  const int h = lane >> 3;
  const int c4 = lane & 7;

  const float* offq = off + (size_t)bq * 256 + h * 32;
  const float* attq = attnlg + (size_t)bq * 128 + h * 16;

  constexpr int LS[4] = {0, 16384, 20480, 21504};

  float4 acc = make_float4(0.f, 0.f, 0.f, 0.f);

#pragma unroll
  for (int l = 0; l < 4; ++l) {
    const int Wl = 128 >> l;
    const int sh = 7 - l;
    const float4* vl4 = v4 + ((size_t)b * NV_ + LS[l]) * 64 + h * 8 + c4;

    // softmax over the 4 points of this (h, l)
    float lg0 = attq[l * 4 + 0];
    float lg1 = attq[l * 4 + 1];
    float lg2 = attq[l * 4 + 2];
    float lg3 = attq[l * 4 + 3];
    float m = fmaxf(fmaxf(lg0, lg1), fmaxf(lg2, lg3));
    float e0 = expf(lg0 - m), e1 = expf(lg1 - m);
    float e2 = expf(lg2 - m), e3 = expf(lg3 - m);
    float inv = 1.f / (e0 + e1 + e2 + e3);
    float wts[4] = {e0 * inv, e1 * inv, e2 * inv, e3 * inv};

    const float s = 0.5f * (float)(Wl - 1);

#pragma unroll
    for (int p = 0; p < 4; ++p) {
      float gx = offq[(l * 4 + p) * 2 + 0];
      float gy = offq[(l * 4 + p) * 2 + 1];
      float px = fmaf(gx, s, s);
      float py = fmaf(gy, s, s);
      float x0f = floorf(px), y0f = floorf(py);
      float wx = px - x0f, wy = py - y0f;
      int x0 = (int)x0f, y0 = (int)y0f;

      bool bx0 = (unsigned)x0 < (unsigned)Wl;
      bool bx1 = (unsigned)(x0 + 1) < (unsigned)Wl;
      bool by0 = (unsigned)y0 < (unsigned)Wl;
      bool by1 = (unsigned)(y0 + 1) < (unsigned)Wl;

      // clamp each corner coordinate independently
      int x0c = min(max(x0, 0), Wl - 1);
      int x1c = min(max(x0 + 1, 0), Wl - 1);
      int y0c = min(max(y0, 0), Wl - 1);
      int y1c = min(max(y0 + 1, 0), Wl - 1);

      float4 v00 = vl4[((y0c << sh) + x0c) * 64];
      float4 v01 = vl4[((y0c << sh) + x1c) * 64];
      float4 v10 = vl4[((y1c << sh) + x0c) * 64];
      float4 v11 = vl4[((y1c << sh) + x1c) * 64];

      float a = wts[p];
      float wxm = 1.f - wx, wym = 1.f - wy;
      float w00 = (bx0 & by0) ? a * wxm * wym : 0.f;
      float w01 = (bx1 & by0) ? a * wx  * wym : 0.f;
      float w10 = (bx0 & by1) ? a * wxm * wy  : 0.f;
      float w11 = (bx1 & by1) ? a * wx  * wy  : 0.f;

      acc.x += w00 * v00.x + w01 * v01.x + w10 * v10.x + w11 * v11.x;
      acc.y += w00 * v00.y + w01 * v01.y + w10 * v10.y + w11 * v11.y;
      acc.z += w00 * v00.z + w01 * v01.z + w10 * v10.z + w11 * v11.z;
      acc.w += w00 * v00.w + w01 * v01.w + w10 * v10.w + w11 * v11.w;
    }
  }
  tmp4[(size_t)bq * 64 + lane] = acc;
}

// ---------------------------------------------------------------------------
extern "C" void kernel_launch(void* const* d_in, const int* in_sizes, int n_in,
                              void* d_out, int out_size, void* d_ws, size_t ws_size,
                              hipStream_t stream) {
  const float* query  = (const float*)d_in[0];
  // d_in[1] = key (unused by the reference)
  const float* value  = (const float*)d_in[2];
  const float* W_off  = (const float*)d_in[3];
  const float* b_off  = (const float*)d_in[4];
  const float* W_attn = (const float*)d_in[5];
  const float* b_attn = (const float*)d_in[6];
  const float* W_v    = (const float*)d_in[7];
  const float* b_v    = (const float*)d_in[8];
  const float* W_out  = (const float*)d_in[9];
  const float* b_out  = (const float*)d_in[10];
  float* out = (float*)d_out;

  float* ws = (float*)d_ws;
  float* v_ws   = ws;                               // 43520*256 floats
  float* off_ws = v_ws + (size_t)B_ * NV_ * EMB;    // 20000*256
  float* att_ws = off_ws + (size_t)B_ * NQ_ * EMB;  // 20000*128
  float* tmp_ws = att_ws + (size_t)B_ * NQ_ * 128;  // 20000*256

  dim3 blk(256);

  {  // v = value @ W_v + b_v
    int M = B_ * NV_;
    gemm_bias<<<dim3((M + 63) / 64, EMB / 64), blk, 0, stream>>>(
        value, W_v, b_v, v_ws, M, EMB);
  }
  {  // off = query @ W_off + b_off ; attn = query @ W_attn + b_attn
    int M = B_ * NQ_;
    gemm_bias<<<dim3((M + 63) / 64, EMB / 64), blk, 0, stream>>>(
        query, W_off, b_off, off_ws, M, EMB);
    gemm_bias<<<dim3((M + 63) / 64, 128 / 64), blk, 0, stream>>>(
        query, W_attn, b_attn, att_ws, M, 128);
  }
  // bilinear sampling + softmax-weighted accumulation (1 wave / query)
  msda_sample2<<<dim3(B_ * NQ_ / 4), blk, 0, stream>>>(
      (const float4*)v_ws, off_ws, att_ws, (float4*)tmp_ws);

  {  // out = tmp @ W_out + b_out
    int M = B_ * NQ_;
    gemm_bias<<<dim3((M + 63) / 64, EMB / 64), blk, 0, stream>>>(
        tmp_ws, W_out, b_out, out, M, EMB);
  }
}

// Round 5
// 166.064 us; speedup vs baseline: 2.6757x; 1.7139x over previous
//
#include <hip/hip_runtime.h>
#include <math.h>

#define B_   2
#define NQ_  10000
#define NV_  21760
#define EMB  256
#define MQ   (B_*NQ_)   // 20000
#define MV   (B_*NV_)   // 43520

typedef short bf16x8 __attribute__((ext_vector_type(8)));
typedef float f32x4  __attribute__((ext_vector_type(4)));

__device__ __forceinline__ unsigned short f2bf(float x) {
  unsigned u = __builtin_bit_cast(unsigned, x);
  u += 0x7FFFu + ((u >> 16) & 1u);
  return (unsigned short)(u >> 16);
}
__device__ __forceinline__ float bf2f(unsigned short s) {
  return __builtin_bit_cast(float, (unsigned)s << 16);
}

// ---------------------------------------------------------------------------
// Weight prep: transpose + bf16-convert all weight matrices once.
// W row-major [K=256][N]  ->  W_t [N][256] bf16.  W_off also gets a lo part.
// ---------------------------------------------------------------------------
__global__ __launch_bounds__(256) void prep_weights(
    const float* __restrict__ Wv, const float* __restrict__ Wattn,
    const float* __restrict__ Woff, const float* __restrict__ Wout,
    unsigned short* __restrict__ WvT, unsigned short* __restrict__ WattnT,
    unsigned short* __restrict__ WoffHiT, unsigned short* __restrict__ WoffLoT,
    unsigned short* __restrict__ WoutT) {
  int n = blockIdx.x;       // 0..895
  int k = threadIdx.x;      // 0..255
  if (n < 256) {
    WvT[n * 256 + k] = f2bf(Wv[k * 256 + n]);
  } else if (n < 384) {
    int c = n - 256;
    WattnT[c * 256 + k] = f2bf(Wattn[k * 128 + c]);
  } else if (n < 640) {
    int c = n - 384;
    WoutT[c * 256 + k] = f2bf(Wout[k * 256 + c]);
  } else {
    int c = n - 640;
    float x = Woff[k * 256 + c];
    unsigned short hi = f2bf(x);
    WoffHiT[c * 256 + k] = hi;
    WoffLoT[c * 256 + k] = f2bf(x - bf2f(hi));
  }
}

// ---------------------------------------------------------------------------
// query -> q_hi (bf16) + q_lo (bf16 residual). grid*256 covers MQ*64 float4s.
// ---------------------------------------------------------------------------
__global__ __launch_bounds__(256) void split_query(
    const float4* __restrict__ q, ushort4* __restrict__ qhi,
    ushort4* __restrict__ qlo) {
  int i = blockIdx.x * 256 + threadIdx.x;
  float4 v = q[i];
  ushort4 h, l;
  h.x = f2bf(v.x); l.x = f2bf(v.x - bf2f(h.x));
  h.y = f2bf(v.y); l.y = f2bf(v.y - bf2f(h.y));
  h.z = f2bf(v.z); l.z = f2bf(v.z - bf2f(h.z));
  h.w = f2bf(v.w); l.w = f2bf(v.w - bf2f(h.w));
  qhi[i] = h; qlo[i] = l;
}

// ---------------------------------------------------------------------------
// MFMA GEMM: C[M,N] = A[M,256] @ W + bias, via v_mfma_f32_16x16x32_bf16.
// W passed as W_t [N][256] bf16 (pre-transposed). 128x128 tile, BK=32,
// 256 threads = 4 waves in 2x2, each wave 64x64 via 4x4 16x16 frags.
// LDS tiles XOR-swizzled so staging writes and ds_read_b128 are <=2-way.
// MODE 0: A bf16. MODE 1: A fp32, converted during staging.
// MODE 2: bf16x3 split GEMM: C = Ahi@Whi + Alo@Whi + Ahi@Wlo  (off-proj).
// ---------------------------------------------------------------------------
template <int MODE, typename OutT>
__global__ __launch_bounds__(256) void gemm_mfma(
    const void* __restrict__ Aa, const void* __restrict__ Ab,
    const unsigned short* __restrict__ Bt, const unsigned short* __restrict__ Bt2,
    const float* __restrict__ bias, OutT* __restrict__ C, int M, int N) {
  constexpr int BM = 128, BK = 32;
  __shared__ unsigned short As[(MODE == 2 ? 2 : 1) * BM * BK];
  __shared__ unsigned short Bs[(MODE == 2 ? 2 : 1) * BM * BK];
  unsigned short* As2 = As + BM * BK;
  unsigned short* Bs2 = Bs + BM * BK;

  const int tid = threadIdx.x;
  const int lane = tid & 63, wv = tid >> 6;
  const int wr = wv >> 1, wc = wv & 1;
  const int row0 = blockIdx.x * BM, col0 = blockIdx.y * BM;

  auto lds_addr = [](int row, int kslot) -> int {
    return row * 64 + ((kslot ^ ((row >> 1) & 3)) << 4);
  };

  auto stage_bf = [&](unsigned short* dst, const unsigned short* src,
                      int rbase, int rmax, int kk) {
#pragma unroll
    for (int i = 0; i < 2; ++i) {
      int idx = tid + 256 * i;          // 512 x 16B
      int row = idx >> 2, ks = idx & 3;
      int rg = min(rbase + row, rmax);
      bf16x8 vdat = *(const bf16x8*)(src + (size_t)rg * 256 + kk + ks * 8);
      *(bf16x8*)((char*)dst + lds_addr(row, ks)) = vdat;
    }
  };
  auto stage_cvt = [&](unsigned short* dst, const float* src,
                       int rbase, int rmax, int kk) {
#pragma unroll
    for (int i = 0; i < 4; ++i) {
      int idx = tid + 256 * i;          // 1024 x float4
      int row = idx >> 3, c4 = idx & 7;
      int rg = min(rbase + row, rmax);
      float4 vdat = *(const float4*)(src + (size_t)rg * 256 + kk + c4 * 4);
      ushort4 o;
      o.x = f2bf(vdat.x); o.y = f2bf(vdat.y);
      o.z = f2bf(vdat.z); o.w = f2bf(vdat.w);
      *(ushort4*)((char*)dst + lds_addr(row, c4 >> 1) + (c4 & 1) * 8) = o;
    }
  };

  f32x4 acc[4][4] = {};

  for (int kk = 0; kk < 256; kk += BK) {
    if (kk) __syncthreads();
    if constexpr (MODE == 1)
      stage_cvt(As, (const float*)Aa, row0, M - 1, kk);
    else
      stage_bf(As, (const unsigned short*)Aa, row0, M - 1, kk);
    stage_bf(Bs, Bt, col0, N - 1, kk);
    if constexpr (MODE == 2) {
      stage_bf(As2, (const unsigned short*)Ab, row0, M - 1, kk);
      stage_bf(Bs2, Bt2, col0, N - 1, kk);
    }
    __syncthreads();

    const int kslot = lane >> 4;
    bf16x8 af[4], bfr[4];
#pragma unroll
    for (int i = 0; i < 4; ++i) {
      int ra = wr * 64 + i * 16 + (lane & 15);
      af[i] = *(const bf16x8*)((const char*)As + lds_addr(ra, kslot));
      int rb = wc * 64 + i * 16 + (lane & 15);
      bfr[i] = *(const bf16x8*)((const char*)Bs + lds_addr(rb, kslot));
    }
#pragma unroll
    for (int mi = 0; mi < 4; ++mi)
#pragma unroll
      for (int ni = 0; ni < 4; ++ni)
        acc[mi][ni] = __builtin_amdgcn_mfma_f32_16x16x32_bf16(
            af[mi], bfr[ni], acc[mi][ni], 0, 0, 0);

    if constexpr (MODE == 2) {
      bf16x8 af2[4], bfr2[4];
#pragma unroll
      for (int i = 0; i < 4; ++i) {
        int ra = wr * 64 + i * 16 + (lane & 15);
        af2[i] = *(const bf16x8*)((const char*)As2 + lds_addr(ra, kslot));
        int rb = wc * 64 + i * 16 + (lane & 15);
        bfr2[i] = *(const bf16x8*)((const char*)Bs2 + lds_addr(rb, kslot));
      }
#pragma unroll
      for (int mi = 0; mi < 4; ++mi)
#pragma unroll
        for (int ni = 0; ni < 4; ++ni) {
          acc[mi][ni] = __builtin_amdgcn_mfma_f32_16x16x32_bf16(
              af2[mi], bfr[ni], acc[mi][ni], 0, 0, 0);   // lo @ hi
          acc[mi][ni] = __builtin_amdgcn_mfma_f32_16x16x32_bf16(
              af[mi], bfr2[ni], acc[mi][ni], 0, 0, 0);   // hi @ lo
        }
    }
  }

  // epilogue: D frag layout col=lane&15, row=(lane>>4)*4+reg  [m89-verified]
#pragma unroll
  for (int ni = 0; ni < 4; ++ni) {
    int col = col0 + wc * 64 + ni * 16 + (lane & 15);
    float bb = bias[col];
#pragma unroll
    for (int mi = 0; mi < 4; ++mi) {
      int rowbase = row0 + wr * 64 + mi * 16 + ((lane >> 4) << 2);
      f32x4 a = acc[mi][ni];
#pragma unroll
      for (int r = 0; r < 4; ++r) {
        int row = rowbase + r;
        if (row < M) {
          float val = a[r] + bb;
          if constexpr (sizeof(OutT) == 2)
            C[(size_t)row * N + col] = (OutT)f2bf(val);
          else
            C[(size_t)row * N + col] = (OutT)val;
        }
      }
    }
  }
}

// ---------------------------------------------------------------------------
// Sampling v3: one wave per query; lane -> head h = lane>>3, chan4 = lane&7.
// v bf16: corner fetch = ushort4 (8 B) per lane, 64 B per head-corner.
// ---------------------------------------------------------------------------
__device__ __forceinline__ float4 bf4tof4(ushort4 u) {
  float4 r;
  r.x = bf2f(u.x); r.y = bf2f(u.y); r.z = bf2f(u.z); r.w = bf2f(u.w);
  return r;
}

__global__ __launch_bounds__(256) void msda_sample3(
    const ushort4* __restrict__ v4, const float* __restrict__ off,
    const float* __restrict__ attnlg, ushort4* __restrict__ tmp4) {
  const int lane = threadIdx.x & 63;
  const int bq = blockIdx.x * 4 + (threadIdx.x >> 6);
  const int b = bq / NQ_;
  const int h = lane >> 3;
  const int c4 = lane & 7;

  const float* offq = off + (size_t)bq * 256 + h * 32;
  const float* attq = attnlg + (size_t)bq * 128 + h * 16;

  constexpr int LS[4] = {0, 16384, 20480, 21504};

  float4 acc = make_float4(0.f, 0.f, 0.f, 0.f);

#pragma unroll
  for (int l = 0; l < 4; ++l) {
    const int Wl = 128 >> l;
    const int sh = 7 - l;
    const ushort4* vl4 = v4 + ((size_t)b * NV_ + LS[l]) * 64 + h * 8 + c4;

    float lg0 = attq[l * 4 + 0];
    float lg1 = attq[l * 4 + 1];
    float lg2 = attq[l * 4 + 2];
    float lg3 = attq[l * 4 + 3];
    float m = fmaxf(fmaxf(lg0, lg1), fmaxf(lg2, lg3));
    float e0 = expf(lg0 - m), e1 = expf(lg1 - m);
    float e2 = expf(lg2 - m), e3 = expf(lg3 - m);
    float inv = 1.f / (e0 + e1 + e2 + e3);
    float wts[4] = {e0 * inv, e1 * inv, e2 * inv, e3 * inv};

    const float s = 0.5f * (float)(Wl - 1);

#pragma unroll
    for (int p = 0; p < 4; ++p) {
      float gx = offq[(l * 4 + p) * 2 + 0];
      float gy = offq[(l * 4 + p) * 2 + 1];
      float px = fmaf(gx, s, s);
      float py = fmaf(gy, s, s);
      float x0f = floorf(px), y0f = floorf(py);
      float wx = px - x0f, wy = py - y0f;
      int x0 = (int)x0f, y0 = (int)y0f;

      bool bx0 = (unsigned)x0 < (unsigned)Wl;
      bool bx1 = (unsigned)(x0 + 1) < (unsigned)Wl;
      bool by0 = (unsigned)y0 < (unsigned)Wl;
      bool by1 = (unsigned)(y0 + 1) < (unsigned)Wl;

      int x0c = min(max(x0, 0), Wl - 1);
      int x1c = min(max(x0 + 1, 0), Wl - 1);
      int y0c = min(max(y0, 0), Wl - 1);
      int y1c = min(max(y0 + 1, 0), Wl - 1);

      float4 v00 = bf4tof4(vl4[((y0c << sh) + x0c) * 64]);
      float4 v01 = bf4tof4(vl4[((y0c << sh) + x1c) * 64]);
      float4 v10 = bf4tof4(vl4[((y1c << sh) + x0c) * 64]);
      float4 v11 = bf4tof4(vl4[((y1c << sh) + x1c) * 64]);

      float a = wts[p];
      float wxm = 1.f - wx, wym = 1.f - wy;
      float w00 = (bx0 & by0) ? a * wxm * wym : 0.f;
      float w01 = (bx1 & by0) ? a * wx  * wym : 0.f;
      float w10 = (bx0 & by1) ? a * wxm * wy  : 0.f;
      float w11 = (bx1 & by1) ? a * wx  * wy  : 0.f;

      acc.x += w00 * v00.x + w01 * v01.x + w10 * v10.x + w11 * v11.x;
      acc.y += w00 * v00.y + w01 * v01.y + w10 * v10.y + w11 * v11.y;
      acc.z += w00 * v00.z + w01 * v01.z + w10 * v10.z + w11 * v11.z;
      acc.w += w00 * v00.w + w01 * v01.w + w10 * v10.w + w11 * v11.w;
    }
  }
  ushort4 o;
  o.x = f2bf(acc.x); o.y = f2bf(acc.y); o.z = f2bf(acc.z); o.w = f2bf(acc.w);
  tmp4[(size_t)bq * 64 + lane] = o;
}

// ---------------------------------------------------------------------------
extern "C" void kernel_launch(void* const* d_in, const int* in_sizes, int n_in,
                              void* d_out, int out_size, void* d_ws, size_t ws_size,
                              hipStream_t stream) {
  const float* query  = (const float*)d_in[0];
  // d_in[1] = key (unused)
  const float* value  = (const float*)d_in[2];
  const float* W_off  = (const float*)d_in[3];
  const float* b_off  = (const float*)d_in[4];
  const float* W_attn = (const float*)d_in[5];
  const float* b_attn = (const float*)d_in[6];
  const float* W_v    = (const float*)d_in[7];
  const float* b_v    = (const float*)d_in[8];
  const float* W_out  = (const float*)d_in[9];
  const float* b_out  = (const float*)d_in[10];
  float* out = (float*)d_out;

  char* p = (char*)d_ws;
  unsigned short* v_bf  = (unsigned short*)p; p += (size_t)MV * 256 * 2;   // 22.3 MB
  unsigned short* q_hi  = (unsigned short*)p; p += (size_t)MQ * 256 * 2;   // 10.2 MB
  unsigned short* q_lo  = (unsigned short*)p; p += (size_t)MQ * 256 * 2;   // 10.2 MB
  float*          off_w = (float*)p;          p += (size_t)MQ * 256 * 4;   // 20.5 MB
  float*          att_w = (float*)p;          p += (size_t)MQ * 128 * 4;   // 10.2 MB
  unsigned short* tmp_bf= (unsigned short*)p; p += (size_t)MQ * 256 * 2;   // 10.2 MB
  unsigned short* WvT   = (unsigned short*)p; p += 256 * 256 * 2;
  unsigned short* WattnT= (unsigned short*)p; p += 128 * 256 * 2;
  unsigned short* WoffHi= (unsigned short*)p; p += 256 * 256 * 2;
  unsigned short* WoffLo= (unsigned short*)p; p += 256 * 256 * 2;
  unsigned short* WoutT = (unsigned short*)p; p += 256 * 256 * 2;

  dim3 blk(256);

  prep_weights<<<dim3(896), blk, 0, stream>>>(
      W_v, W_attn, W_off, W_out, WvT, WattnT, WoffHi, WoffLo, WoutT);

  split_query<<<dim3(MQ / 4), blk, 0, stream>>>(
      (const float4*)query, (ushort4*)q_hi, (ushort4*)q_lo);

  // v = value @ W_v + b_v  (fp32 A converted in staging; bf16 output)
  gemm_mfma<1, unsigned short><<<dim3(MV / 128, 2), blk, 0, stream>>>(
      value, nullptr, WvT, nullptr, b_v, v_bf, MV, 256);

  // attn logits = q_hi @ W_attn + b_attn  (fp32 out)
  gemm_mfma<0, float><<<dim3((MQ + 127) / 128, 1), blk, 0, stream>>>(
      q_hi, nullptr, WattnT, nullptr, b_attn, att_w, MQ, 128);

  // off = (q_hi+q_lo) @ (Whi+Wlo) + b_off  (bf16x3, fp32 out)
  gemm_mfma<2, float><<<dim3((MQ + 127) / 128, 2), blk, 0, stream>>>(
      q_hi, q_lo, WoffHi, WoffLo, b_off, off_w, MQ, 256);

  // bilinear sampling + softmax-weighted accumulation (1 wave / query)
  msda_sample3<<<dim3(MQ / 4), blk, 0, stream>>>(
      (const ushort4*)v_bf, off_w, att_w, (ushort4*)tmp_bf);

  // out = tmp @ W_out + b_out  (fp32 out)
  gemm_mfma<0, float><<<dim3((MQ + 127) / 128, 2), blk, 0, stream>>>(
      tmp_bf, nullptr, WoutT, nullptr, b_out, out, MQ, 256);
}

// Round 6
// 146.388 us; speedup vs baseline: 3.0353x; 1.1344x over previous
//
#include <hip/hip_runtime.h>
#include <math.h>

#define B_   2
#define NQ_  10000
#define NV_  21760
#define EMB  256
#define MQ   (B_*NQ_)   // 20000
#define MV   (B_*NV_)   // 43520

typedef short bf16x8 __attribute__((ext_vector_type(8)));
typedef float f32x4  __attribute__((ext_vector_type(4)));

__device__ __forceinline__ unsigned short f2bf(float x) {
  unsigned u = __builtin_bit_cast(unsigned, x);
  u += 0x7FFFu + ((u >> 16) & 1u);
  return (unsigned short)(u >> 16);
}
__device__ __forceinline__ float bf2f(unsigned short s) {
  return __builtin_bit_cast(float, (unsigned)s << 16);
}

// ---------------------------------------------------------------------------
// Weight prep: transpose + bf16-convert weights.
//  n<256   : WvT   [256][256] hi
//  n<512   : WoutT [256][256] hi
//  n<896   : WqHi/WqLo [384][256]  rows 0-255 = W_off cols, 256-383 = W_attn
// ---------------------------------------------------------------------------
__global__ __launch_bounds__(256) void prep_weights(
    const float* __restrict__ Wv, const float* __restrict__ Wattn,
    const float* __restrict__ Woff, const float* __restrict__ Wout,
    unsigned short* __restrict__ WvT, unsigned short* __restrict__ WoutT,
    unsigned short* __restrict__ WqHi, unsigned short* __restrict__ WqLo) {
  int n = blockIdx.x;       // 0..895
  int k = threadIdx.x;      // 0..255
  if (n < 256) {
    WvT[n * 256 + k] = f2bf(Wv[k * 256 + n]);
  } else if (n < 512) {
    int c = n - 256;
    WoutT[c * 256 + k] = f2bf(Wout[k * 256 + c]);
  } else {
    int qr = n - 512;       // 0..383
    float x = (qr < 256) ? Woff[k * 256 + qr] : Wattn[k * 128 + (qr - 256)];
    unsigned short hi = f2bf(x);
    WqHi[qr * 256 + k] = hi;
    WqLo[qr * 256 + k] = f2bf(x - bf2f(hi));
  }
}

// ---------------------------------------------------------------------------
// MFMA GEMM, 128x128 tile, BK=32, 4 waves (2x2), 4x4 16x16x32 frags/wave.
// LDS XOR-swizzled (<=2-way on both staging writes and ds_read_b128).
// MODE 0: A bf16 [M][256], 1-term.
// MODE 1: A fp32 [M][256], converted during staging, 1-term.
// MODE 3: A fp32, split hi/lo during staging; B has hi+lo; 3-term
//         (hi@hi + lo@hi + hi@lo). Dual output: cols<256 -> C, else -> C2.
// ---------------------------------------------------------------------------
template <int MODE, typename OutT>
__global__ __launch_bounds__(256) void gemm_mfma(
    const void* __restrict__ Aa,
    const unsigned short* __restrict__ Bt, const unsigned short* __restrict__ Bt2,
    const float* __restrict__ bias, const float* __restrict__ bias2,
    OutT* __restrict__ C, float* __restrict__ C2, int M, int N) {
  constexpr int BM = 128, BK = 32;
  __shared__ unsigned short As[(MODE == 3 ? 2 : 1) * BM * BK];
  __shared__ unsigned short Bs[(MODE == 3 ? 2 : 1) * BM * BK];
  unsigned short* As2 = As + BM * BK;
  unsigned short* Bs2 = Bs + BM * BK;

  const int tid = threadIdx.x;
  const int lane = tid & 63, wv = tid >> 6;
  const int wr = wv >> 1, wc = wv & 1;
  const int row0 = blockIdx.x * BM, col0 = blockIdx.y * BM;

  auto lds_addr = [](int row, int kslot) -> int {
    return row * 64 + ((kslot ^ ((row >> 1) & 3)) << 4);
  };

  auto stage_bf = [&](unsigned short* dst, const unsigned short* src,
                      int rbase, int rmax, int kk) {
#pragma unroll
    for (int i = 0; i < 2; ++i) {
      int idx = tid + 256 * i;          // 512 x 16B
      int row = idx >> 2, ks = idx & 3;
      int rg = min(rbase + row, rmax);
      bf16x8 vdat = *(const bf16x8*)(src + (size_t)rg * 256 + kk + ks * 8);
      *(bf16x8*)((char*)dst + lds_addr(row, ks)) = vdat;
    }
  };
  auto stage_cvt = [&](unsigned short* dst, const float* src,
                       int rbase, int rmax, int kk) {
#pragma unroll
    for (int i = 0; i < 4; ++i) {
      int idx = tid + 256 * i;          // 1024 x float4
      int row = idx >> 3, c4 = idx & 7;
      int rg = min(rbase + row, rmax);
      float4 vdat = *(const float4*)(src + (size_t)rg * 256 + kk + c4 * 4);
      ushort4 o;
      o.x = f2bf(vdat.x); o.y = f2bf(vdat.y);
      o.z = f2bf(vdat.z); o.w = f2bf(vdat.w);
      *(ushort4*)((char*)dst + lds_addr(row, c4 >> 1) + (c4 & 1) * 8) = o;
    }
  };
  auto stage_cvt2 = [&](unsigned short* dstH, unsigned short* dstL,
                        const float* src, int rbase, int rmax, int kk) {
#pragma unroll
    for (int i = 0; i < 4; ++i) {
      int idx = tid + 256 * i;
      int row = idx >> 3, c4 = idx & 7;
      int rg = min(rbase + row, rmax);
      float4 vdat = *(const float4*)(src + (size_t)rg * 256 + kk + c4 * 4);
      ushort4 hh, ll;
      hh.x = f2bf(vdat.x); ll.x = f2bf(vdat.x - bf2f(hh.x));
      hh.y = f2bf(vdat.y); ll.y = f2bf(vdat.y - bf2f(hh.y));
      hh.z = f2bf(vdat.z); ll.z = f2bf(vdat.z - bf2f(hh.z));
      hh.w = f2bf(vdat.w); ll.w = f2bf(vdat.w - bf2f(hh.w));
      int a = lds_addr(row, c4 >> 1) + (c4 & 1) * 8;
      *(ushort4*)((char*)dstH + a) = hh;
      *(ushort4*)((char*)dstL + a) = ll;
    }
  };

  f32x4 acc[4][4] = {};

  for (int kk = 0; kk < 256; kk += BK) {
    if (kk) __syncthreads();
    if constexpr (MODE == 1)
      stage_cvt(As, (const float*)Aa, row0, M - 1, kk);
    else if constexpr (MODE == 3)
      stage_cvt2(As, As2, (const float*)Aa, row0, M - 1, kk);
    else
      stage_bf(As, (const unsigned short*)Aa, row0, M - 1, kk);
    stage_bf(Bs, Bt, col0, N - 1, kk);
    if constexpr (MODE == 3)
      stage_bf(Bs2, Bt2, col0, N - 1, kk);
    __syncthreads();

    const int kslot = lane >> 4;
    bf16x8 af[4], bfr[4];
#pragma unroll
    for (int i = 0; i < 4; ++i) {
      int ra = wr * 64 + i * 16 + (lane & 15);
      af[i] = *(const bf16x8*)((const char*)As + lds_addr(ra, kslot));
      int rb = wc * 64 + i * 16 + (lane & 15);
      bfr[i] = *(const bf16x8*)((const char*)Bs + lds_addr(rb, kslot));
    }
#pragma unroll
    for (int mi = 0; mi < 4; ++mi)
#pragma unroll
      for (int ni = 0; ni < 4; ++ni)
        acc[mi][ni] = __builtin_amdgcn_mfma_f32_16x16x32_bf16(
            af[mi], bfr[ni], acc[mi][ni], 0, 0, 0);

    if constexpr (MODE == 3) {
      bf16x8 af2[4], bfr2[4];
#pragma unroll
      for (int i = 0; i < 4; ++i) {
        int ra = wr * 64 + i * 16 + (lane & 15);
        af2[i] = *(const bf16x8*)((const char*)As2 + lds_addr(ra, kslot));
        int rb = wc * 64 + i * 16 + (lane & 15);
        bfr2[i] = *(const bf16x8*)((const char*)Bs2 + lds_addr(rb, kslot));
      }
#pragma unroll
      for (int mi = 0; mi < 4; ++mi)
#pragma unroll
        for (int ni = 0; ni < 4; ++ni) {
          acc[mi][ni] = __builtin_amdgcn_mfma_f32_16x16x32_bf16(
              af2[mi], bfr[ni], acc[mi][ni], 0, 0, 0);   // lo @ hi
          acc[mi][ni] = __builtin_amdgcn_mfma_f32_16x16x32_bf16(
              af[mi], bfr2[ni], acc[mi][ni], 0, 0, 0);   // hi @ lo
        }
    }
  }

  // epilogue: D frag layout col=lane&15, row=(lane>>4)*4+reg  [m89-verified]
#pragma unroll
  for (int ni = 0; ni < 4; ++ni) {
    int gcol = col0 + wc * 64 + ni * 16 + (lane & 15);
    float bb = (MODE == 3 && gcol >= 256) ? bias2[gcol - 256] : bias[gcol];
#pragma unroll
    for (int mi = 0; mi < 4; ++mi) {
      int rowbase = row0 + wr * 64 + mi * 16 + ((lane >> 4) << 2);
      f32x4 a = acc[mi][ni];
#pragma unroll
      for (int r = 0; r < 4; ++r) {
        int row = rowbase + r;
        if (row < M) {
          float val = a[r] + bb;
          if constexpr (MODE == 3) {
            if (gcol >= 256)
              C2[(size_t)row * 128 + (gcol - 256)] = val;
            else
              C[(size_t)row * 256 + gcol] = (OutT)val;
          } else if constexpr (sizeof(OutT) == 2) {
            C[(size_t)row * N + gcol] = (OutT)f2bf(val);
          } else {
            C[(size_t)row * N + gcol] = (OutT)val;
          }
        }
      }
    }
  }
}

// ---------------------------------------------------------------------------
// Sampling v4: one wave per query (block = 4 queries).
// Phase 1: lane owns combos c = lane, lane+64 (c = h*16+l*4+p): computes
//   softmax weight, bilinear coords, independent clamps -> 4 packed u16
//   indices + 4 fp32 corner weights -> LDS slot (32 B, skew +32 B per h).
// Phase 2: lane -> (h = lane>>3, c4 = lane&7); per point: 2 LDS reads,
//   4 unpacks, 4 saddr+voffset float4 gathers, 16 fma. v is fp32 so a
//   head-corner is exactly one 128 B line and no cvt is needed.
// ---------------------------------------------------------------------------
__global__ __launch_bounds__(256) void msda_sample4(
    const float* __restrict__ v,      // (B*NV, 256) fp32, (pix, h, d)
    const float* __restrict__ off,    // (MQ, 256)
    const float* __restrict__ attnlg, // (MQ, 128)
    ushort4* __restrict__ tmp4) {     // (MQ, 64) ushort4 = bf16 (h,d)
  __shared__ unsigned coeff[4 * 136 * 8];   // 17408 B
  const int lane = threadIdx.x & 63;
  const int wq = threadIdx.x >> 6;
  const int bq = blockIdx.x * 4 + wq;
  const int b = bq / NQ_;

  unsigned* cbase = coeff + wq * (136 * 8);
  const float* offq = off + (size_t)bq * 256;
  const float* attq = attnlg + (size_t)bq * 128;

  // ---- phase 1
#pragma unroll
  for (int i = 0; i < 2; ++i) {
    int c = lane + i * 64;
    int h = c >> 4, l = (c >> 2) & 3, p = c & 3;
    int Wl = 128 >> l, sh = 7 - l;

    const float* lg = attq + h * 16 + l * 4;
    float l0 = lg[0], l1 = lg[1], l2 = lg[2], l3 = lg[3];
    float m = fmaxf(fmaxf(l0, l1), fmaxf(l2, l3));
    float e0 = expf(l0 - m), e1 = expf(l1 - m);
    float e2 = expf(l2 - m), e3 = expf(l3 - m);
    float ep = (p == 0) ? e0 : (p == 1) ? e1 : (p == 2) ? e2 : e3;
    float wsm = ep / (e0 + e1 + e2 + e3);

    float gx = offq[h * 32 + (l * 4 + p) * 2 + 0];
    float gy = offq[h * 32 + (l * 4 + p) * 2 + 1];
    float s = 0.5f * (float)(Wl - 1);
    float px = fmaf(gx, s, s), py = fmaf(gy, s, s);
    float x0f = floorf(px), y0f = floorf(py);
    float wx = px - x0f, wy = py - y0f;
    int x0 = (int)x0f, y0 = (int)y0f;

    bool bx0 = (unsigned)x0 < (unsigned)Wl, bx1 = (unsigned)(x0 + 1) < (unsigned)Wl;
    bool by0 = (unsigned)y0 < (unsigned)Wl, by1 = (unsigned)(y0 + 1) < (unsigned)Wl;
    int x0c = min(max(x0, 0), Wl - 1), x1c = min(max(x0 + 1, 0), Wl - 1);
    int y0c = min(max(y0, 0), Wl - 1), y1c = min(max(y0 + 1, 0), Wl - 1);

    unsigned i00 = (unsigned)((y0c << sh) + x0c), i01 = (unsigned)((y0c << sh) + x1c);
    unsigned i10 = (unsigned)((y1c << sh) + x0c), i11 = (unsigned)((y1c << sh) + x1c);

    float wxm = 1.f - wx, wym = 1.f - wy;
    float w00 = (bx0 & by0) ? wsm * wxm * wym : 0.f;
    float w01 = (bx1 & by0) ? wsm * wx  * wym : 0.f;
    float w10 = (bx0 & by1) ? wsm * wxm * wy  : 0.f;
    float w11 = (bx1 & by1) ? wsm * wx  * wy  : 0.f;

    unsigned* slot = cbase + (c + h) * 8;   // skew: slot index = h*17 + l*4 + p
    uint4 s0;
    s0.x = i00 | (i01 << 16);
    s0.y = i10 | (i11 << 16);
    s0.z = __builtin_bit_cast(unsigned, w00);
    s0.w = __builtin_bit_cast(unsigned, w01);
    *(uint4*)slot = s0;
    uint2 s1;
    s1.x = __builtin_bit_cast(unsigned, w10);
    s1.y = __builtin_bit_cast(unsigned, w11);
    *(uint2*)(slot + 4) = s1;
  }
  __syncthreads();

  // ---- phase 2
  const int h = lane >> 3, c4 = lane & 7;
  constexpr int LS[4] = {0, 16384, 20480, 21504};
  const char* vbase = (const char*)v;
  float4 acc = make_float4(0.f, 0.f, 0.f, 0.f);

#pragma unroll
  for (int l = 0; l < 4; ++l) {
    const unsigned lvl_off =
        ((unsigned)b * NV_ + (unsigned)LS[l]) * 1024u + (unsigned)(h * 128 + c4 * 16);
    const unsigned* cb = cbase + (h * 17 + l * 4) * 8;
#pragma unroll
    for (int p = 0; p < 4; ++p) {
      uint4 s0 = *(const uint4*)(cb + p * 8);
      uint2 s1 = *(const uint2*)(cb + p * 8 + 4);
      unsigned i00 = s0.x & 0xFFFFu, i01 = s0.x >> 16;
      unsigned i10 = s0.y & 0xFFFFu, i11 = s0.y >> 16;
      float w00 = __builtin_bit_cast(float, s0.z);
      float w01 = __builtin_bit_cast(float, s0.w);
      float w10 = __builtin_bit_cast(float, s1.x);
      float w11 = __builtin_bit_cast(float, s1.y);

      float4 v00 = *(const float4*)(vbase + (lvl_off + (i00 << 10)));
      float4 v01 = *(const float4*)(vbase + (lvl_off + (i01 << 10)));
      float4 v10 = *(const float4*)(vbase + (lvl_off + (i10 << 10)));
      float4 v11 = *(const float4*)(vbase + (lvl_off + (i11 << 10)));

      acc.x += w00 * v00.x + w01 * v01.x + w10 * v10.x + w11 * v11.x;
      acc.y += w00 * v00.y + w01 * v01.y + w10 * v10.y + w11 * v11.y;
      acc.z += w00 * v00.z + w01 * v01.z + w10 * v10.z + w11 * v11.z;
      acc.w += w00 * v00.w + w01 * v01.w + w10 * v10.w + w11 * v11.w;
    }
  }
  ushort4 o;
  o.x = f2bf(acc.x); o.y = f2bf(acc.y); o.z = f2bf(acc.z); o.w = f2bf(acc.w);
  tmp4[(size_t)bq * 64 + lane] = o;
}

// ---------------------------------------------------------------------------
extern "C" void kernel_launch(void* const* d_in, const int* in_sizes, int n_in,
                              void* d_out, int out_size, void* d_ws, size_t ws_size,
                              hipStream_t stream) {
  const float* query  = (const float*)d_in[0];
  // d_in[1] = key (unused)
  const float* value  = (const float*)d_in[2];
  const float* W_off  = (const float*)d_in[3];
  const float* b_off  = (const float*)d_in[4];
  const float* W_attn = (const float*)d_in[5];
  const float* b_attn = (const float*)d_in[6];
  const float* W_v    = (const float*)d_in[7];
  const float* b_v    = (const float*)d_in[8];
  const float* W_out  = (const float*)d_in[9];
  const float* b_out  = (const float*)d_in[10];
  float* out = (float*)d_out;

  char* p = (char*)d_ws;
  float*          v_f   = (float*)p;          p += (size_t)MV * 256 * 4;   // 44.6 MB
  float*          off_w = (float*)p;          p += (size_t)MQ * 256 * 4;   // 20.5 MB
  float*          att_w = (float*)p;          p += (size_t)MQ * 128 * 4;   // 10.2 MB
  unsigned short* tmp_bf= (unsigned short*)p; p += (size_t)MQ * 256 * 2;   // 10.2 MB
  unsigned short* WvT   = (unsigned short*)p; p += 256 * 256 * 2;
  unsigned short* WoutT = (unsigned short*)p; p += 256 * 256 * 2;
  unsigned short* WqHi  = (unsigned short*)p; p += 384 * 256 * 2;
  unsigned short* WqLo  = (unsigned short*)p; p += 384 * 256 * 2;

  dim3 blk(256);

  prep_weights<<<dim3(896), blk, 0, stream>>>(
      W_v, W_attn, W_off, W_out, WvT, WoutT, WqHi, WqLo);

  // v = value @ W_v + b_v  (fp32 out)
  gemm_mfma<1, float><<<dim3(MV / 128, 2), blk, 0, stream>>>(
      value, WvT, nullptr, b_v, nullptr, v_f, nullptr, MV, 256);

  // fused query projections: cols 0-255 -> off (fp32), 256-383 -> attn (fp32)
  // 3-term bf16 split on everything (query hi/lo made during staging).
  gemm_mfma<3, float><<<dim3((MQ + 127) / 128, 3), blk, 0, stream>>>(
      query, WqHi, WqLo, b_off, b_attn, off_w, att_w, MQ, 384);

  // bilinear sampling + softmax-weighted accumulation
  msda_sample4<<<dim3(MQ / 4), blk, 0, stream>>>(
      v_f, off_w, att_w, (ushort4*)tmp_bf);

  // out = tmp @ W_out + b_out
  gemm_mfma<0, float><<<dim3((MQ + 127) / 128, 2), blk, 0, stream>>>(
      tmp_bf, WoutT, nullptr, b_out, nullptr, out, nullptr, MQ, 256);
}

// Round 7
// 136.147 us; speedup vs baseline: 3.2636x; 1.0752x over previous
//
#include <hip/hip_runtime.h>
#include <math.h>

#define B_   2
#define NQ_  10000
#define NV_  21760
#define EMB  256
#define MQ   (B_*NQ_)   // 20000
#define MV   (B_*NV_)   // 43520

typedef short bf16x8 __attribute__((ext_vector_type(8)));
typedef float f32x4  __attribute__((ext_vector_type(4)));

__device__ __forceinline__ unsigned short f2bf(float x) {
  unsigned u = __builtin_bit_cast(unsigned, x);
  u += 0x7FFFu + ((u >> 16) & 1u);
  return (unsigned short)(u >> 16);
}
__device__ __forceinline__ float bf2f(unsigned short s) {
  return __builtin_bit_cast(float, (unsigned)s << 16);
}

// ---------------------------------------------------------------------------
// Weight prep: transpose + bf16-convert weights.
//  n<256   : WvT   [256][256] hi
//  n<512   : WoutT [256][256] hi
//  n<896   : WqHi/WqLo [384][256]  rows 0-255 = W_off cols, 256-383 = W_attn
// ---------------------------------------------------------------------------
__global__ __launch_bounds__(256) void prep_weights(
    const float* __restrict__ Wv, const float* __restrict__ Wattn,
    const float* __restrict__ Woff, const float* __restrict__ Wout,
    unsigned short* __restrict__ WvT, unsigned short* __restrict__ WoutT,
    unsigned short* __restrict__ WqHi, unsigned short* __restrict__ WqLo) {
  int n = blockIdx.x;       // 0..895
  int k = threadIdx.x;      // 0..255
  if (n < 256) {
    WvT[n * 256 + k] = f2bf(Wv[k * 256 + n]);
  } else if (n < 512) {
    int c = n - 256;
    WoutT[c * 256 + k] = f2bf(Wout[k * 256 + c]);
  } else {
    int qr = n - 512;       // 0..383
    float x = (qr < 256) ? Woff[k * 256 + qr] : Wattn[k * 128 + (qr - 256)];
    unsigned short hi = f2bf(x);
    WqHi[qr * 256 + k] = hi;
    WqLo[qr * 256 + k] = f2bf(x - bf2f(hi));
  }
}

// ---------------------------------------------------------------------------
// MFMA GEMM, 128x128 tile, BK=32, 4 waves (2x2), 4x4 16x16x32 frags/wave.
// LDS XOR-swizzled (<=2-way on both staging writes and ds_read_b128).
// MODE 0: A bf16 [M][256], 1-term.
// MODE 1: A fp32 [M][256], converted during staging, 1-term.
// MODE 3: A fp32, split hi/lo during staging; B has hi+lo; 3-term
//         (hi@hi + lo@hi + hi@lo). Dual output: cols<256 -> C, else -> C2.
// ---------------------------------------------------------------------------
template <int MODE, typename OutT>
__global__ __launch_bounds__(256) void gemm_mfma(
    const void* __restrict__ Aa,
    const unsigned short* __restrict__ Bt, const unsigned short* __restrict__ Bt2,
    const float* __restrict__ bias, const float* __restrict__ bias2,
    OutT* __restrict__ C, float* __restrict__ C2, int M, int N) {
  constexpr int BM = 128, BK = 32;
  __shared__ unsigned short As[(MODE == 3 ? 2 : 1) * BM * BK];
  __shared__ unsigned short Bs[(MODE == 3 ? 2 : 1) * BM * BK];
  unsigned short* As2 = As + BM * BK;
  unsigned short* Bs2 = Bs + BM * BK;

  const int tid = threadIdx.x;
  const int lane = tid & 63, wv = tid >> 6;
  const int wr = wv >> 1, wc = wv & 1;
  const int row0 = blockIdx.x * BM, col0 = blockIdx.y * BM;

  auto lds_addr = [](int row, int kslot) -> int {
    return row * 64 + ((kslot ^ ((row >> 1) & 3)) << 4);
  };

  auto stage_bf = [&](unsigned short* dst, const unsigned short* src,
                      int rbase, int rmax, int kk) {
#pragma unroll
    for (int i = 0; i < 2; ++i) {
      int idx = tid + 256 * i;          // 512 x 16B
      int row = idx >> 2, ks = idx & 3;
      int rg = min(rbase + row, rmax);
      bf16x8 vdat = *(const bf16x8*)(src + (size_t)rg * 256 + kk + ks * 8);
      *(bf16x8*)((char*)dst + lds_addr(row, ks)) = vdat;
    }
  };
  auto stage_cvt = [&](unsigned short* dst, const float* src,
                       int rbase, int rmax, int kk) {
#pragma unroll
    for (int i = 0; i < 4; ++i) {
      int idx = tid + 256 * i;          // 1024 x float4
      int row = idx >> 3, c4 = idx & 7;
      int rg = min(rbase + row, rmax);
      float4 vdat = *(const float4*)(src + (size_t)rg * 256 + kk + c4 * 4);
      ushort4 o;
      o.x = f2bf(vdat.x); o.y = f2bf(vdat.y);
      o.z = f2bf(vdat.z); o.w = f2bf(vdat.w);
      *(ushort4*)((char*)dst + lds_addr(row, c4 >> 1) + (c4 & 1) * 8) = o;
    }
  };
  auto stage_cvt2 = [&](unsigned short* dstH, unsigned short* dstL,
                        const float* src, int rbase, int rmax, int kk) {
#pragma unroll
    for (int i = 0; i < 4; ++i) {
      int idx = tid + 256 * i;
      int row = idx >> 3, c4 = idx & 7;
      int rg = min(rbase + row, rmax);
      float4 vdat = *(const float4*)(src + (size_t)rg * 256 + kk + c4 * 4);
      ushort4 hh, ll;
      hh.x = f2bf(vdat.x); ll.x = f2bf(vdat.x - bf2f(hh.x));
      hh.y = f2bf(vdat.y); ll.y = f2bf(vdat.y - bf2f(hh.y));
      hh.z = f2bf(vdat.z); ll.z = f2bf(vdat.z - bf2f(hh.z));
      hh.w = f2bf(vdat.w); ll.w = f2bf(vdat.w - bf2f(hh.w));
      int a = lds_addr(row, c4 >> 1) + (c4 & 1) * 8;
      *(ushort4*)((char*)dstH + a) = hh;
      *(ushort4*)((char*)dstL + a) = ll;
    }
  };

  f32x4 acc[4][4] = {};

  for (int kk = 0; kk < 256; kk += BK) {
    if (kk) __syncthreads();
    if constexpr (MODE == 1)
      stage_cvt(As, (const float*)Aa, row0, M - 1, kk);
    else if constexpr (MODE == 3)
      stage_cvt2(As, As2, (const float*)Aa, row0, M - 1, kk);
    else
      stage_bf(As, (const unsigned short*)Aa, row0, M - 1, kk);
    stage_bf(Bs, Bt, col0, N - 1, kk);
    if constexpr (MODE == 3)
      stage_bf(Bs2, Bt2, col0, N - 1, kk);
    __syncthreads();

    const int kslot = lane >> 4;
    bf16x8 af[4], bfr[4];
#pragma unroll
    for (int i = 0; i < 4; ++i) {
      int ra = wr * 64 + i * 16 + (lane & 15);
      af[i] = *(const bf16x8*)((const char*)As + lds_addr(ra, kslot));
      int rb = wc * 64 + i * 16 + (lane & 15);
      bfr[i] = *(const bf16x8*)((const char*)Bs + lds_addr(rb, kslot));
    }
#pragma unroll
    for (int mi = 0; mi < 4; ++mi)
#pragma unroll
      for (int ni = 0; ni < 4; ++ni)
        acc[mi][ni] = __builtin_amdgcn_mfma_f32_16x16x32_bf16(
            af[mi], bfr[ni], acc[mi][ni], 0, 0, 0);

    if constexpr (MODE == 3) {
      bf16x8 af2[4], bfr2[4];
#pragma unroll
      for (int i = 0; i < 4; ++i) {
        int ra = wr * 64 + i * 16 + (lane & 15);
        af2[i] = *(const bf16x8*)((const char*)As2 + lds_addr(ra, kslot));
        int rb = wc * 64 + i * 16 + (lane & 15);
        bfr2[i] = *(const bf16x8*)((const char*)Bs2 + lds_addr(rb, kslot));
      }
#pragma unroll
      for (int mi = 0; mi < 4; ++mi)
#pragma unroll
        for (int ni = 0; ni < 4; ++ni) {
          acc[mi][ni] = __builtin_amdgcn_mfma_f32_16x16x32_bf16(
              af2[mi], bfr[ni], acc[mi][ni], 0, 0, 0);   // lo @ hi
          acc[mi][ni] = __builtin_amdgcn_mfma_f32_16x16x32_bf16(
              af[mi], bfr2[ni], acc[mi][ni], 0, 0, 0);   // hi @ lo
        }
    }
  }

  // epilogue: D frag layout col=lane&15, row=(lane>>4)*4+reg  [m89-verified]
#pragma unroll
  for (int ni = 0; ni < 4; ++ni) {
    int gcol = col0 + wc * 64 + ni * 16 + (lane & 15);
    float bb = (MODE == 3 && gcol >= 256) ? bias2[gcol - 256] : bias[gcol];
#pragma unroll
    for (int mi = 0; mi < 4; ++mi) {
      int rowbase = row0 + wr * 64 + mi * 16 + ((lane >> 4) << 2);
      f32x4 a = acc[mi][ni];
#pragma unroll
      for (int r = 0; r < 4; ++r) {
        int row = rowbase + r;
        if (row < M) {
          float val = a[r] + bb;
          if constexpr (MODE == 3) {
            if (gcol >= 256)
              C2[(size_t)row * 128 + (gcol - 256)] = val;
            else
              C[(size_t)row * 256 + gcol] = (OutT)val;
          } else if constexpr (sizeof(OutT) == 2) {
            C[(size_t)row * N + gcol] = (OutT)f2bf(val);
          } else {
            C[(size_t)row * N + gcol] = (OutT)val;
          }
        }
      }
    }
  }
}

// ---------------------------------------------------------------------------
// Sampling v5: one wave per query (block = 4 queries).
// Phase 1 (coeff precompute, as R6): lane owns combos c = lane, lane+64:
//   softmax weight, coords, independent clamps -> 4 packed u16 indices +
//   4 fp32 corner weights -> skewed LDS slot.
// Phase 2: lane -> (h = lane>>3, c4 = lane&7). v is bf16 (pix,h,d):
//   corner = uint2 (8 B/lane, 64 B/head — 2 heads per 128 B line, halving
//   L2 line traffic vs fp32). Unpack bf16 pairs with shift/and (no cvt).
// ---------------------------------------------------------------------------
__global__ __launch_bounds__(256) void msda_sample5(
    const unsigned short* __restrict__ v,  // (B*NV, 256) bf16, (pix, h, d)
    const float* __restrict__ off,         // (MQ, 256)
    const float* __restrict__ attnlg,      // (MQ, 128)
    ushort4* __restrict__ tmp4) {          // (MQ, 64) ushort4 = bf16 (h,d)
  __shared__ unsigned coeff[4 * 136 * 8];   // 17408 B
  const int lane = threadIdx.x & 63;
  const int wq = threadIdx.x >> 6;
  const int bq = blockIdx.x * 4 + wq;
  const int b = bq / NQ_;

  unsigned* cbase = coeff + wq * (136 * 8);
  const float* offq = off + (size_t)bq * 256;
  const float* attq = attnlg + (size_t)bq * 128;

  // ---- phase 1
#pragma unroll
  for (int i = 0; i < 2; ++i) {
    int c = lane + i * 64;
    int h = c >> 4, l = (c >> 2) & 3, p = c & 3;
    int Wl = 128 >> l, sh = 7 - l;

    const float* lg = attq + h * 16 + l * 4;
    float l0 = lg[0], l1 = lg[1], l2 = lg[2], l3 = lg[3];
    float m = fmaxf(fmaxf(l0, l1), fmaxf(l2, l3));
    float e0 = expf(l0 - m), e1 = expf(l1 - m);
    float e2 = expf(l2 - m), e3 = expf(l3 - m);
    float ep = (p == 0) ? e0 : (p == 1) ? e1 : (p == 2) ? e2 : e3;
    float wsm = ep / (e0 + e1 + e2 + e3);

    float gx = offq[h * 32 + (l * 4 + p) * 2 + 0];
    float gy = offq[h * 32 + (l * 4 + p) * 2 + 1];
    float s = 0.5f * (float)(Wl - 1);
    float px = fmaf(gx, s, s), py = fmaf(gy, s, s);
    float x0f = floorf(px), y0f = floorf(py);
    float wx = px - x0f, wy = py - y0f;
    int x0 = (int)x0f, y0 = (int)y0f;

    bool bx0 = (unsigned)x0 < (unsigned)Wl, bx1 = (unsigned)(x0 + 1) < (unsigned)Wl;
    bool by0 = (unsigned)y0 < (unsigned)Wl, by1 = (unsigned)(y0 + 1) < (unsigned)Wl;
    int x0c = min(max(x0, 0), Wl - 1), x1c = min(max(x0 + 1, 0), Wl - 1);
    int y0c = min(max(y0, 0), Wl - 1), y1c = min(max(y0 + 1, 0), Wl - 1);

    unsigned i00 = (unsigned)((y0c << sh) + x0c), i01 = (unsigned)((y0c << sh) + x1c);
    unsigned i10 = (unsigned)((y1c << sh) + x0c), i11 = (unsigned)((y1c << sh) + x1c);

    float wxm = 1.f - wx, wym = 1.f - wy;
    float w00 = (bx0 & by0) ? wsm * wxm * wym : 0.f;
    float w01 = (bx1 & by0) ? wsm * wx  * wym : 0.f;
    float w10 = (bx0 & by1) ? wsm * wxm * wy  : 0.f;
    float w11 = (bx1 & by1) ? wsm * wx  * wy  : 0.f;

    unsigned* slot = cbase + (c + h) * 8;   // skew: slot index = h*17 + l*4 + p
    uint4 s0;
    s0.x = i00 | (i01 << 16);
    s0.y = i10 | (i11 << 16);
    s0.z = __builtin_bit_cast(unsigned, w00);
    s0.w = __builtin_bit_cast(unsigned, w01);
    *(uint4*)slot = s0;
    uint2 s1;
    s1.x = __builtin_bit_cast(unsigned, w10);
    s1.y = __builtin_bit_cast(unsigned, w11);
    *(uint2*)(slot + 4) = s1;
  }
  __syncthreads();

  // ---- phase 2
  const int h = lane >> 3, c4 = lane & 7;
  constexpr int LS[4] = {0, 16384, 20480, 21504};
  const char* vbase = (const char*)v;
  float4 acc = make_float4(0.f, 0.f, 0.f, 0.f);

#pragma unroll
  for (int l = 0; l < 4; ++l) {
    // byte offset of (pixel 0, head h, chan 4*c4) at this level; row = 512 B
    const unsigned lvl_off =
        ((unsigned)b * NV_ + (unsigned)LS[l]) * 512u + (unsigned)(h * 64 + c4 * 8);
    const unsigned* cb = cbase + (h * 17 + l * 4) * 8;
#pragma unroll
    for (int p = 0; p < 4; ++p) {
      uint4 s0 = *(const uint4*)(cb + p * 8);
      uint2 s1 = *(const uint2*)(cb + p * 8 + 4);
      unsigned i00 = s0.x & 0xFFFFu, i01 = s0.x >> 16;
      unsigned i10 = s0.y & 0xFFFFu, i11 = s0.y >> 16;
      float w00 = __builtin_bit_cast(float, s0.z);
      float w01 = __builtin_bit_cast(float, s0.w);
      float w10 = __builtin_bit_cast(float, s1.x);
      float w11 = __builtin_bit_cast(float, s1.y);

      uint2 r00 = *(const uint2*)(vbase + (lvl_off + (i00 << 9)));
      uint2 r01 = *(const uint2*)(vbase + (lvl_off + (i01 << 9)));
      uint2 r10 = *(const uint2*)(vbase + (lvl_off + (i10 << 9)));
      uint2 r11 = *(const uint2*)(vbase + (lvl_off + (i11 << 9)));

      // unpack bf16 pairs: lo -> <<16, hi -> & 0xFFFF0000
      acc.x += w00 * __builtin_bit_cast(float, r00.x << 16)
             + w01 * __builtin_bit_cast(float, r01.x << 16)
             + w10 * __builtin_bit_cast(float, r10.x << 16)
             + w11 * __builtin_bit_cast(float, r11.x << 16);
      acc.y += w00 * __builtin_bit_cast(float, r00.x & 0xFFFF0000u)
             + w01 * __builtin_bit_cast(float, r01.x & 0xFFFF0000u)
             + w10 * __builtin_bit_cast(float, r10.x & 0xFFFF0000u)
             + w11 * __builtin_bit_cast(float, r11.x & 0xFFFF0000u);
      acc.z += w00 * __builtin_bit_cast(float, r00.y << 16)
             + w01 * __builtin_bit_cast(float, r01.y << 16)
             + w10 * __builtin_bit_cast(float, r10.y << 16)
             + w11 * __builtin_bit_cast(float, r11.y << 16);
      acc.w += w00 * __builtin_bit_cast(float, r00.y & 0xFFFF0000u)
             + w01 * __builtin_bit_cast(float, r01.y & 0xFFFF0000u)
             + w10 * __builtin_bit_cast(float, r10.y & 0xFFFF0000u)
             + w11 * __builtin_bit_cast(float, r11.y & 0xFFFF0000u);
    }
  }
  ushort4 o;
  o.x = f2bf(acc.x); o.y = f2bf(acc.y); o.z = f2bf(acc.z); o.w = f2bf(acc.w);
  tmp4[(size_t)bq * 64 + lane] = o;
}

// ---------------------------------------------------------------------------
extern "C" void kernel_launch(void* const* d_in, const int* in_sizes, int n_in,
                              void* d_out, int out_size, void* d_ws, size_t ws_size,
                              hipStream_t stream) {
  const float* query  = (const float*)d_in[0];
  // d_in[1] = key (unused)
  const float* value  = (const float*)d_in[2];
  const float* W_off  = (const float*)d_in[3];
  const float* b_off  = (const float*)d_in[4];
  const float* W_attn = (const float*)d_in[5];
  const float* b_attn = (const float*)d_in[6];
  const float* W_v    = (const float*)d_in[7];
  const float* b_v    = (const float*)d_in[8];
  const float* W_out  = (const float*)d_in[9];
  const float* b_out  = (const float*)d_in[10];
  float* out = (float*)d_out;

  char* p = (char*)d_ws;
  unsigned short* v_bf  = (unsigned short*)p; p += (size_t)MV * 256 * 2;   // 22.3 MB
  float*          off_w = (float*)p;          p += (size_t)MQ * 256 * 4;   // 20.5 MB
  float*          att_w = (float*)p;          p += (size_t)MQ * 128 * 4;   // 10.2 MB
  unsigned short* tmp_bf= (unsigned short*)p; p += (size_t)MQ * 256 * 2;   // 10.2 MB
  unsigned short* WvT   = (unsigned short*)p; p += 256 * 256 * 2;
  unsigned short* WoutT = (unsigned short*)p; p += 256 * 256 * 2;
  unsigned short* WqHi  = (unsigned short*)p; p += 384 * 256 * 2;
  unsigned short* WqLo  = (unsigned short*)p; p += 384 * 256 * 2;

  dim3 blk(256);

  prep_weights<<<dim3(896), blk, 0, stream>>>(
      W_v, W_attn, W_off, W_out, WvT, WoutT, WqHi, WqLo);

  // v = value @ W_v + b_v  (bf16 out for the sampler)
  gemm_mfma<1, unsigned short><<<dim3(MV / 128, 2), blk, 0, stream>>>(
      value, WvT, nullptr, b_v, nullptr, v_bf, nullptr, MV, 256);

  // fused query projections: cols 0-255 -> off (fp32), 256-383 -> attn (fp32)
  gemm_mfma<3, float><<<dim3((MQ + 127) / 128, 3), blk, 0, stream>>>(
      query, WqHi, WqLo, b_off, b_attn, off_w, att_w, MQ, 384);

  // bilinear sampling + softmax-weighted accumulation
  msda_sample5<<<dim3(MQ / 4), blk, 0, stream>>>(
      v_bf, off_w, att_w, (ushort4*)tmp_bf);

  // out = tmp @ W_out + b_out
  gemm_mfma<0, float><<<dim3((MQ + 127) / 128, 2), blk, 0, stream>>>(
      tmp_bf, WoutT, nullptr, b_out, nullptr, out, nullptr, MQ, 256);
}

// Round 8
// 125.523 us; speedup vs baseline: 3.5399x; 1.0846x over previous
//
#include <hip/hip_runtime.h>
#include <math.h>

#define B_   2
#define NQ_  10000
#define NV_  21760
#define EMB  256
#define MQ   (B_*NQ_)   // 20000
#define MV   (B_*NV_)   // 43520

typedef short bf16x8 __attribute__((ext_vector_type(8)));
typedef float f32x4  __attribute__((ext_vector_type(4)));

__device__ constexpr int LSc[4] = {0, 16384, 20480, 21504};

__device__ __forceinline__ unsigned short f2bf(float x) {
  unsigned u = __builtin_bit_cast(unsigned, x);
  u += 0x7FFFu + ((u >> 16) & 1u);
  return (unsigned short)(u >> 16);
}
__device__ __forceinline__ float bf2f(unsigned short s) {
  return __builtin_bit_cast(float, (unsigned)s << 16);
}

// ---------------------------------------------------------------------------
// Weight prep: transpose + bf16-convert weights.
//  n<256 : WvT[256][256]; n<512 : WoutT[256][256];
//  n<896 : WqHi/WqLo[384][256] (rows 0-255 = W_off cols, 256-383 = W_attn)
// ---------------------------------------------------------------------------
__global__ __launch_bounds__(256) void prep_weights(
    const float* __restrict__ Wv, const float* __restrict__ Wattn,
    const float* __restrict__ Woff, const float* __restrict__ Wout,
    unsigned short* __restrict__ WvT, unsigned short* __restrict__ WoutT,
    unsigned short* __restrict__ WqHi, unsigned short* __restrict__ WqLo) {
  int n = blockIdx.x;       // 0..895
  int k = threadIdx.x;      // 0..255
  if (n < 256) {
    WvT[n * 256 + k] = f2bf(Wv[k * 256 + n]);
  } else if (n < 512) {
    int c = n - 256;
    WoutT[c * 256 + k] = f2bf(Wout[k * 256 + c]);
  } else {
    int qr = n - 512;       // 0..383
    float x = (qr < 256) ? Woff[k * 256 + qr] : Wattn[k * 128 + (qr - 256)];
    unsigned short hi = f2bf(x);
    WqHi[qr * 256 + k] = hi;
    WqLo[qr * 256 + k] = f2bf(x - bf2f(hi));
  }
}

// ---------------------------------------------------------------------------
// MFMA GEMM, 128x128 tile, BK=32, 4 waves (2x2), 4x4 16x16x32 frags/wave.
// LDS XOR-swizzled (<=2-way on staging writes and ds_read_b128).
// MODE 0: A bf16, 1-term.   MODE 1: A fp32 (cvt in staging), 1-term.
// MODE 3: A fp32 split hi/lo in staging; 3-term for col0<256 (off cols),
//         1-term for col0>=256 (attn cols). Dual output C / C2.
// VPERM:  epilogue scatters bf16 into the x-pair-packed v layout:
//         byte = (b*NV+LS[l])*512 + ((y*(W/2)+x/2)<<10) + ((x&1)<<3)
//                + h*128 + (d>>2)*16 + (d&3)*2
// ---------------------------------------------------------------------------
template <int MODE, typename OutT, bool VPERM = false>
__global__ __launch_bounds__(256) void gemm_mfma(
    const void* __restrict__ Aa,
    const unsigned short* __restrict__ Bt, const unsigned short* __restrict__ Bt2,
    const float* __restrict__ bias, const float* __restrict__ bias2,
    OutT* __restrict__ C, float* __restrict__ C2, int M, int N) {
  constexpr int BM = 128, BK = 32;
  __shared__ unsigned short As[(MODE == 3 ? 2 : 1) * BM * BK];
  __shared__ unsigned short Bs[(MODE == 3 ? 2 : 1) * BM * BK];
  unsigned short* As2 = As + BM * BK;
  unsigned short* Bs2 = Bs + BM * BK;

  const int tid = threadIdx.x;
  const int lane = tid & 63, wv = tid >> 6;
  const int wr = wv >> 1, wc = wv & 1;
  const int row0 = blockIdx.x * BM, col0 = blockIdx.y * BM;

  auto lds_addr = [](int row, int kslot) -> int {
    return row * 64 + ((kslot ^ ((row >> 1) & 3)) << 4);
  };

  auto stage_bf = [&](unsigned short* dst, const unsigned short* src,
                      int rbase, int rmax, int kk) {
#pragma unroll
    for (int i = 0; i < 2; ++i) {
      int idx = tid + 256 * i;          // 512 x 16B
      int row = idx >> 2, ks = idx & 3;
      int rg = min(rbase + row, rmax);
      bf16x8 vdat = *(const bf16x8*)(src + (size_t)rg * 256 + kk + ks * 8);
      *(bf16x8*)((char*)dst + lds_addr(row, ks)) = vdat;
    }
  };
  auto stage_cvt = [&](unsigned short* dst, const float* src,
                       int rbase, int rmax, int kk) {
#pragma unroll
    for (int i = 0; i < 4; ++i) {
      int idx = tid + 256 * i;          // 1024 x float4
      int row = idx >> 3, c4 = idx & 7;
      int rg = min(rbase + row, rmax);
      float4 vdat = *(const float4*)(src + (size_t)rg * 256 + kk + c4 * 4);
      ushort4 o;
      o.x = f2bf(vdat.x); o.y = f2bf(vdat.y);
      o.z = f2bf(vdat.z); o.w = f2bf(vdat.w);
      *(ushort4*)((char*)dst + lds_addr(row, c4 >> 1) + (c4 & 1) * 8) = o;
    }
  };
  auto stage_cvt2 = [&](unsigned short* dstH, unsigned short* dstL,
                        const float* src, int rbase, int rmax, int kk) {
#pragma unroll
    for (int i = 0; i < 4; ++i) {
      int idx = tid + 256 * i;
      int row = idx >> 3, c4 = idx & 7;
      int rg = min(rbase + row, rmax);
      float4 vdat = *(const float4*)(src + (size_t)rg * 256 + kk + c4 * 4);
      ushort4 hh, ll;
      hh.x = f2bf(vdat.x); ll.x = f2bf(vdat.x - bf2f(hh.x));
      hh.y = f2bf(vdat.y); ll.y = f2bf(vdat.y - bf2f(hh.y));
      hh.z = f2bf(vdat.z); ll.z = f2bf(vdat.z - bf2f(hh.z));
      hh.w = f2bf(vdat.w); ll.w = f2bf(vdat.w - bf2f(hh.w));
      int a = lds_addr(row, c4 >> 1) + (c4 & 1) * 8;
      *(ushort4*)((char*)dstH + a) = hh;
      *(ushort4*)((char*)dstL + a) = ll;
    }
  };

  const bool three_term = (MODE == 3) && (col0 < 256);

  f32x4 acc[4][4] = {};

  for (int kk = 0; kk < 256; kk += BK) {
    if (kk) __syncthreads();
    if constexpr (MODE == 1)
      stage_cvt(As, (const float*)Aa, row0, M - 1, kk);
    else if constexpr (MODE == 3) {
      if (three_term)
        stage_cvt2(As, As2, (const float*)Aa, row0, M - 1, kk);
      else
        stage_cvt(As, (const float*)Aa, row0, M - 1, kk);
    } else
      stage_bf(As, (const unsigned short*)Aa, row0, M - 1, kk);
    stage_bf(Bs, Bt, col0, N - 1, kk);
    if constexpr (MODE == 3)
      if (three_term) stage_bf(Bs2, Bt2, col0, N - 1, kk);
    __syncthreads();

    const int kslot = lane >> 4;
    bf16x8 af[4], bfr[4];
#pragma unroll
    for (int i = 0; i < 4; ++i) {
      int ra = wr * 64 + i * 16 + (lane & 15);
      af[i] = *(const bf16x8*)((const char*)As + lds_addr(ra, kslot));
      int rb = wc * 64 + i * 16 + (lane & 15);
      bfr[i] = *(const bf16x8*)((const char*)Bs + lds_addr(rb, kslot));
    }
#pragma unroll
    for (int mi = 0; mi < 4; ++mi)
#pragma unroll
      for (int ni = 0; ni < 4; ++ni)
        acc[mi][ni] = __builtin_amdgcn_mfma_f32_16x16x32_bf16(
            af[mi], bfr[ni], acc[mi][ni], 0, 0, 0);

    if constexpr (MODE == 3) {
      if (three_term) {
        bf16x8 af2[4], bfr2[4];
#pragma unroll
        for (int i = 0; i < 4; ++i) {
          int ra = wr * 64 + i * 16 + (lane & 15);
          af2[i] = *(const bf16x8*)((const char*)As2 + lds_addr(ra, kslot));
          int rb = wc * 64 + i * 16 + (lane & 15);
          bfr2[i] = *(const bf16x8*)((const char*)Bs2 + lds_addr(rb, kslot));
        }
#pragma unroll
        for (int mi = 0; mi < 4; ++mi)
#pragma unroll
          for (int ni = 0; ni < 4; ++ni) {
            acc[mi][ni] = __builtin_amdgcn_mfma_f32_16x16x32_bf16(
                af2[mi], bfr[ni], acc[mi][ni], 0, 0, 0);   // lo @ hi
            acc[mi][ni] = __builtin_amdgcn_mfma_f32_16x16x32_bf16(
                af[mi], bfr2[ni], acc[mi][ni], 0, 0, 0);   // hi @ lo
          }
      }
    }
  }

  // epilogue: D frag layout col=lane&15, row=(lane>>4)*4+reg  [m89-verified]
  if constexpr (VPERM) {
    float bb4[4];
#pragma unroll
    for (int ni = 0; ni < 4; ++ni)
      bb4[ni] = bias[col0 + wc * 64 + ni * 16 + (lane & 15)];
#pragma unroll
    for (int mi = 0; mi < 4; ++mi) {
#pragma unroll
      for (int r = 0; r < 4; ++r) {
        int row = row0 + wr * 64 + mi * 16 + ((lane >> 4) << 2) + r;
        int pix = row, bb2 = 0;
        if (pix >= NV_) { bb2 = 1; pix -= NV_; }
        int lvl = (pix >= 16384) + (pix >= 20480) + (pix >= 21504);
        int sh = 7 - lvl;
        int rel = pix - LSc[lvl];
        int x = rel & ((1 << sh) - 1), y = rel >> sh;
        unsigned pairoff = ((unsigned)((y << (sh - 1)) + (x >> 1)) << 10) |
                           ((unsigned)(x & 1) << 3);
        char* vout = (char*)C + ((size_t)bb2 * NV_ + LSc[lvl]) * 512 + pairoff;
#pragma unroll
        for (int ni = 0; ni < 4; ++ni) {
          int gcol = col0 + wc * 64 + ni * 16 + (lane & 15);
          float val = acc[mi][ni][r] + bb4[ni];
          int h = gcol >> 5, d = gcol & 31;
          *(unsigned short*)(vout + h * 128 + (d >> 2) * 16 + (d & 3) * 2) =
              f2bf(val);
        }
      }
    }
  } else {
#pragma unroll
    for (int ni = 0; ni < 4; ++ni) {
      int gcol = col0 + wc * 64 + ni * 16 + (lane & 15);
      float bb = (MODE == 3 && gcol >= 256) ? bias2[gcol - 256] : bias[gcol];
#pragma unroll
      for (int mi = 0; mi < 4; ++mi) {
        int rowbase = row0 + wr * 64 + mi * 16 + ((lane >> 4) << 2);
        f32x4 a = acc[mi][ni];
#pragma unroll
        for (int r = 0; r < 4; ++r) {
          int row = rowbase + r;
          if (row < M) {
            float val = a[r] + bb;
            if constexpr (MODE == 3) {
              if (gcol >= 256)
                C2[(size_t)row * 128 + (gcol - 256)] = val;
              else
                C[(size_t)row * 256 + gcol] = (OutT)val;
            } else if constexpr (sizeof(OutT) == 2) {
              C[(size_t)row * N + gcol] = (OutT)f2bf(val);
            } else {
              C[(size_t)row * N + gcol] = (OutT)val;
            }
          }
        }
      }
    }
  }
}

// ---------------------------------------------------------------------------
// Sampling v6: one wave per query (block = 4 queries, b uniform per block).
// Phase 1: lane owns combos c = lane, lane+64: softmax weight, coords,
//   independent clamps -> 4 u32 byte-offsets into the pair-packed level
//   (pairoff | parity*8) + 4 fp32 corner weights -> skewed LDS slot (32 B).
// Phase 2: lane -> (h = lane>>3, c4 = lane&7); per point: 2 ds_read_b128,
//   4 x 8-B gathers at scalar-base + 32-bit offset, shift/and bf16 unpack,
//   16 fma. x-adjacent corners share one 128 B line when x0 is even.
// ---------------------------------------------------------------------------
__global__ __launch_bounds__(256) void msda_sample6(
    const char* __restrict__ v,            // pair-packed bf16
    const float* __restrict__ off,         // (MQ, 256)
    const float* __restrict__ attnlg,      // (MQ, 128)
    ushort4* __restrict__ tmp4) {          // (MQ, 64) bf16 (h,d)
  __shared__ unsigned coeff[4 * 136 * 8];   // 17408 B
  const int lane = threadIdx.x & 63;
  const int wq = threadIdx.x >> 6;
  const int bq = blockIdx.x * 4 + wq;
  const int b = (blockIdx.x * 4) / NQ_;     // block-uniform (no straddle)

  unsigned* cbase = coeff + wq * (136 * 8);
  const float* offq = off + (size_t)bq * 256;
  const float* attq = attnlg + (size_t)bq * 128;

  // ---- phase 1
#pragma unroll
  for (int i = 0; i < 2; ++i) {
    int c = lane + i * 64;
    int h = c >> 4, l = (c >> 2) & 3, p = c & 3;
    int Wl = 128 >> l, sh = 7 - l;

    const float* lg = attq + h * 16 + l * 4;
    float l0 = lg[0], l1 = lg[1], l2 = lg[2], l3 = lg[3];
    float m = fmaxf(fmaxf(l0, l1), fmaxf(l2, l3));
    float e0 = expf(l0 - m), e1 = expf(l1 - m);
    float e2 = expf(l2 - m), e3 = expf(l3 - m);
    float ep = (p == 0) ? e0 : (p == 1) ? e1 : (p == 2) ? e2 : e3;
    float wsm = ep / (e0 + e1 + e2 + e3);

    float gx = offq[h * 32 + (l * 4 + p) * 2 + 0];
    float gy = offq[h * 32 + (l * 4 + p) * 2 + 1];
    float s = 0.5f * (float)(Wl - 1);
    float px = fmaf(gx, s, s), py = fmaf(gy, s, s);
    float x0f = floorf(px), y0f = floorf(py);
    float wx = px - x0f, wy = py - y0f;
    int x0 = (int)x0f, y0 = (int)y0f;

    bool bx0 = (unsigned)x0 < (unsigned)Wl, bx1 = (unsigned)(x0 + 1) < (unsigned)Wl;
    bool by0 = (unsigned)y0 < (unsigned)Wl, by1 = (unsigned)(y0 + 1) < (unsigned)Wl;
    int x0c = min(max(x0, 0), Wl - 1), x1c = min(max(x0 + 1, 0), Wl - 1);
    int y0c = min(max(y0, 0), Wl - 1), y1c = min(max(y0 + 1, 0), Wl - 1);

    auto poff = [&](int xx, int yy) -> unsigned {
      return ((unsigned)((yy << (sh - 1)) + (xx >> 1)) << 10) |
             ((unsigned)(xx & 1) << 3);
    };

    float wxm = 1.f - wx, wym = 1.f - wy;
    float w00 = (bx0 & by0) ? wsm * wxm * wym : 0.f;
    float w01 = (bx1 & by0) ? wsm * wx  * wym : 0.f;
    float w10 = (bx0 & by1) ? wsm * wxm * wy  : 0.f;
    float w11 = (bx1 & by1) ? wsm * wx  * wy  : 0.f;

    unsigned* slot = cbase + (c + h) * 8;   // skew: slot = h*17 + l*4 + p
    uint4 s0;
    s0.x = poff(x0c, y0c);
    s0.y = poff(x1c, y0c);
    s0.z = poff(x0c, y1c);
    s0.w = poff(x1c, y1c);
    *(uint4*)slot = s0;
    uint4 s1;
    s1.x = __builtin_bit_cast(unsigned, w00);
    s1.y = __builtin_bit_cast(unsigned, w01);
    s1.z = __builtin_bit_cast(unsigned, w10);
    s1.w = __builtin_bit_cast(unsigned, w11);
    *(uint4*)(slot + 4) = s1;
  }
  __syncthreads();

  // ---- phase 2
  const int h = lane >> 3, c4 = lane & 7;
  const unsigned laneoff = (unsigned)(h * 128 + c4 * 16);
  float4 acc = make_float4(0.f, 0.f, 0.f, 0.f);

#pragma unroll
  for (int l = 0; l < 4; ++l) {
    const char* lb = v + ((size_t)b * NV_ + LSc[l]) * 512;
    const unsigned* cb = cbase + (h * 17 + l * 4) * 8;
#pragma unroll
    for (int p = 0; p < 4; ++p) {
      uint4 s0 = *(const uint4*)(cb + p * 8);
      uint4 s1 = *(const uint4*)(cb + p * 8 + 4);
      float w00 = __builtin_bit_cast(float, s1.x);
      float w01 = __builtin_bit_cast(float, s1.y);
      float w10 = __builtin_bit_cast(float, s1.z);
      float w11 = __builtin_bit_cast(float, s1.w);

      uint2 r00 = *(const uint2*)(lb + (laneoff + s0.x));
      uint2 r01 = *(const uint2*)(lb + (laneoff + s0.y));
      uint2 r10 = *(const uint2*)(lb + (laneoff + s0.z));
      uint2 r11 = *(const uint2*)(lb + (laneoff + s0.w));

      acc.x += w00 * __builtin_bit_cast(float, r00.x << 16)
             + w01 * __builtin_bit_cast(float, r01.x << 16)
             + w10 * __builtin_bit_cast(float, r10.x << 16)
             + w11 * __builtin_bit_cast(float, r11.x << 16);
      acc.y += w00 * __builtin_bit_cast(float, r00.x & 0xFFFF0000u)
             + w01 * __builtin_bit_cast(float, r01.x & 0xFFFF0000u)
             + w10 * __builtin_bit_cast(float, r10.x & 0xFFFF0000u)
             + w11 * __builtin_bit_cast(float, r11.x & 0xFFFF0000u);
      acc.z += w00 * __builtin_bit_cast(float, r00.y << 16)
             + w01 * __builtin_bit_cast(float, r01.y << 16)
             + w10 * __builtin_bit_cast(float, r10.y << 16)
             + w11 * __builtin_bit_cast(float, r11.y << 16);
      acc.w += w00 * __builtin_bit_cast(float, r00.y & 0xFFFF0000u)
             + w01 * __builtin_bit_cast(float, r01.y & 0xFFFF0000u)
             + w10 * __builtin_bit_cast(float, r10.y & 0xFFFF0000u)
             + w11 * __builtin_bit_cast(float, r11.y & 0xFFFF0000u);
    }
  }
  ushort4 o;
  o.x = f2bf(acc.x); o.y = f2bf(acc.y); o.z = f2bf(acc.z); o.w = f2bf(acc.w);
  tmp4[(size_t)bq * 64 + lane] = o;
}

// ---------------------------------------------------------------------------
extern "C" void kernel_launch(void* const* d_in, const int* in_sizes, int n_in,
                              void* d_out, int out_size, void* d_ws, size_t ws_size,
                              hipStream_t stream) {
  const float* query  = (const float*)d_in[0];
  // d_in[1] = key (unused)
  const float* value  = (const float*)d_in[2];
  const float* W_off  = (const float*)d_in[3];
  const float* b_off  = (const float*)d_in[4];
  const float* W_attn = (const float*)d_in[5];
  const float* b_attn = (const float*)d_in[6];
  const float* W_v    = (const float*)d_in[7];
  const float* b_v    = (const float*)d_in[8];
  const float* W_out  = (const float*)d_in[9];
  const float* b_out  = (const float*)d_in[10];
  float* out = (float*)d_out;

  char* p = (char*)d_ws;
  unsigned short* v_bf  = (unsigned short*)p; p += (size_t)MV * 256 * 2;   // 22.3 MB
  float*          off_w = (float*)p;          p += (size_t)MQ * 256 * 4;   // 20.5 MB
  float*          att_w = (float*)p;          p += (size_t)MQ * 128 * 4;   // 10.2 MB
  unsigned short* tmp_bf= (unsigned short*)p; p += (size_t)MQ * 256 * 2;   // 10.2 MB
  unsigned short* WvT   = (unsigned short*)p; p += 256 * 256 * 2;
  unsigned short* WoutT = (unsigned short*)p; p += 256 * 256 * 2;
  unsigned short* WqHi  = (unsigned short*)p; p += 384 * 256 * 2;
  unsigned short* WqLo  = (unsigned short*)p; p += 384 * 256 * 2;

  dim3 blk(256);

  prep_weights<<<dim3(896), blk, 0, stream>>>(
      W_v, W_attn, W_off, W_out, WvT, WoutT, WqHi, WqLo);

  // v = value @ W_v + b_v  (bf16 out, x-pair-packed layout via VPERM)
  gemm_mfma<1, unsigned short, true><<<dim3(MV / 128, 2), blk, 0, stream>>>(
      value, WvT, nullptr, b_v, nullptr, v_bf, nullptr, MV, 256);

  // fused q projections: cols 0-255 -> off (3-term), 256-383 -> attn (1-term)
  gemm_mfma<3, float><<<dim3((MQ + 127) / 128, 3), blk, 0, stream>>>(
      query, WqHi, WqLo, b_off, b_attn, off_w, att_w, MQ, 384);

  // bilinear sampling + softmax-weighted accumulation
  msda_sample6<<<dim3(MQ / 4), blk, 0, stream>>>(
      (const char*)v_bf, off_w, att_w, (ushort4*)tmp_bf);

  // out = tmp @ W_out + b_out
  gemm_mfma<0, float><<<dim3((MQ + 127) / 128, 2), blk, 0, stream>>>(
      tmp_bf, WoutT, nullptr, b_out, nullptr, out, nullptr, MQ, 256);
}